// Round 1
// baseline (31738.739 us; speedup 1.0000x reference)
//
#include <hip/hip_runtime.h>
#include <hip/hip_bf16.h>
#include <cstdio>

#define NBLK 128
#define NTHR 256
#define HH   1024
#define BB   64
#define TT   1024
#define SS   8                 // hidden units per block
#define COLS 32                // 4 gates * SS
#define PITCH 1032             // LDS weight pitch in elements (pad: breaks bank conflicts, keeps 16B align)
#define WELEMS (COLS * PITCH)  // 33024 ushorts per weight matrix slice
#define ZPITCH 33
#define SMEM_BYTES (2 * WELEMS * 2 + 2 * 64 * ZPITCH * 4 + 3 * 32 * 4)  // 149376

typedef __bf16 bf16x8 __attribute__((ext_vector_type(8)));
typedef float  f32x4  __attribute__((ext_vector_type(4)));

__device__ __forceinline__ unsigned short f2bf(float x) {
  unsigned int u = __builtin_bit_cast(unsigned int, x);
  u = (u + 0x7fffu + ((u >> 16) & 1u)) >> 16;   // RNE
  return (unsigned short)u;
}
__device__ __forceinline__ float sigm(float x)  { return 1.f / (1.f + __expf(-x)); }
__device__ __forceinline__ float tanhx(float x) { return 2.f / (1.f + __expf(-2.f * x)) - 1.f; }

// Gather one (1024 x 32) column-slice of a (1024 x 4096) fp32 weight into LDS as bf16,
// layout wt[n][k] with pitch PITCH. Columns of the slice: n = g*8+jj -> g*1024 + colbase + jj.
__device__ __forceinline__ void gather_w(const float* __restrict__ Wg, int colbase,
                                         unsigned short* dst) {
  const int tid = threadIdx.x;
  const int n   = tid & 31;
  const int kg  = tid >> 5;  // 0..7
  const int col = (n >> 3) * HH + colbase + (n & 7);
#pragma unroll 8
  for (int kk = 0; kk < 128; ++kk) {
    const int k = kg * 128 + kk;
    dst[n * PITCH + k] = f2bf(Wg[(size_t)k * 4096 + col]);
  }
}

// Grid barrier: per-period counter in workspace (pre-zeroed). Release flushes this XCD's L2
// to LLC; acquire invalidates L1/L2 so the next period's h reads see fresh data.
__device__ __forceinline__ void grid_barrier(int* counters, int p) {
  __syncthreads();  // all waves' stores have vmcnt(0) drained before s_barrier
  if (threadIdx.x == 0) {
    __hip_atomic_fetch_add(&counters[p], 1, __ATOMIC_RELEASE, __HIP_MEMORY_SCOPE_AGENT);
    while (__hip_atomic_load(&counters[p], __ATOMIC_RELAXED, __HIP_MEMORY_SCOPE_AGENT) < NBLK)
      __builtin_amdgcn_s_sleep(2);
    (void)__hip_atomic_load(&counters[p], __ATOMIC_ACQUIRE, __HIP_MEMORY_SCOPE_AGENT);
  }
  __syncthreads();
}

__global__ void __launch_bounds__(NTHR, 1) lstm_persist(
    const float* __restrict__ x,   const float* __restrict__ Wi0,
    const float* __restrict__ Wh0, const float* __restrict__ b0,
    const float* __restrict__ Wi1, const float* __restrict__ Wh1,
    const float* __restrict__ b1,  float* out,
    int* counters, unsigned short* hbuf) {
  extern __shared__ unsigned short smem_us[];
  unsigned short* w0 = smem_us;                 // phase A: Wh0 slice; phase B: Wi1 slice
  unsigned short* w1 = smem_us + WELEMS;        // phase B: Wh1 slice
  float* zbuf = (float*)(smem_us + 2 * WELEMS); // [2][64][ZPITCH]
  float* wi0s = zbuf + 2 * 64 * ZPITCH;
  float* b0s  = wi0s + 32;
  float* b1s  = b0s + 32;

  const int tid     = threadIdx.x;
  const int lane    = tid & 63;
  const int wv      = tid >> 6;
  const int colbase = blockIdx.x * SS;

  if (tid < 32) {
    const int col = (tid >> 3) * HH + colbase + (tid & 7);
    wi0s[tid] = Wi0[col];
    b0s[tid]  = b0[col];
    b1s[tid]  = b1[col];
  }
  gather_w(Wh0, colbase, w0);
  __syncthreads();

  // pointwise ownership: thread -> (sample ps, hidden pair pj, pj+1)
  const int ps = tid >> 2;
  const int pj = (tid & 3) * 2;
  float c_a = 0.f, c_b = 0.f;              // cell state, layer 0 then layer 1
  float hp2a = 0.f, hp2b = 0.f;            // delayed h2 write regs
  float hl_a = 0.f, hl_b = 0.f;            // final h1 (layer-1 hidden)

  float* h2out = out + 2 * BB * HH;                       // h2 region, fp32 (B,T,H)
  unsigned short* stash = (unsigned short*)h2out;          // bf16 h1-history packed into upper half slots

  const int kq = wv * 256;        // per-wave K-quarter
  const int lm = lane & 15;
  const int lk = (lane >> 4) * 8;
  const f32x4 fzero = {0.f, 0.f, 0.f, 0.f};

  for (int p = 0; p < 2048; ++p) {
    const bool phB = (p >= 1024);
    const int  t   = phB ? (p - 1024) : p;
    const unsigned short* hprev = hbuf + ((p + 1) & 1) * (BB * HH);

    if (p == 1024) {  // phase switch: load layer-1 weights (uniform branch)
      gather_w(Wi1, colbase, w0);
      gather_w(Wh1, colbase, w1);
      __syncthreads();
    }
    // delayed fp32 h2 write for t-1 (safe: all stash[t-1] reads finished last period)
    if (phB && t > 0) {
      float* o = h2out + (size_t)ps * (TT * HH) + (size_t)(t - 1) * HH + colbase + pj;
      o[0] = hp2a; o[1] = hp2b;
    }

    f32x4 acc[4][2];
#pragma unroll
    for (int i = 0; i < 4; ++i)
#pragma unroll
      for (int j = 0; j < 2; ++j) acc[i][j] = fzero;

    // ---- matmul 1: phase A: h_prev @ Wh0 ; phase B: h1_hist[t] @ Wi1 ----
    {
      const unsigned short* Ab;
      size_t Ast;
      if (phB) { Ab = stash + (size_t)t * 2048 + 1024; Ast = 2097152; }
      else     { Ab = hprev;                           Ast = HH; }
#pragma unroll
      for (int kc = 0; kc < 8; ++kc) {
        const int k0 = kq + kc * 32 + lk;
        bf16x8 af[4];
#pragma unroll
        for (int mt = 0; mt < 4; ++mt)
          af[mt] = *reinterpret_cast<const bf16x8*>(Ab + (size_t)(mt * 16 + lm) * Ast + k0);
#pragma unroll
        for (int nt = 0; nt < 2; ++nt) {
          const bf16x8 bfr = *reinterpret_cast<const bf16x8*>(w0 + (nt * 16 + lm) * PITCH + k0);
#pragma unroll
          for (int mt = 0; mt < 4; ++mt)
            acc[mt][nt] = __builtin_amdgcn_mfma_f32_16x16x32_bf16(af[mt], bfr, acc[mt][nt], 0, 0, 0);
        }
      }
    }
    // ---- matmul 2 (phase B only): h1_prev @ Wh1 ----
    if (phB) {
#pragma unroll
      for (int kc = 0; kc < 8; ++kc) {
        const int k0 = kq + kc * 32 + lk;
        bf16x8 af[4];
#pragma unroll
        for (int mt = 0; mt < 4; ++mt)
          af[mt] = *reinterpret_cast<const bf16x8*>(hprev + (size_t)(mt * 16 + lm) * HH + k0);
#pragma unroll
        for (int nt = 0; nt < 2; ++nt) {
          const bf16x8 bfr = *reinterpret_cast<const bf16x8*>(w1 + (nt * 16 + lm) * PITCH + k0);
#pragma unroll
          for (int mt = 0; mt < 4; ++mt)
            acc[mt][nt] = __builtin_amdgcn_mfma_f32_16x16x32_bf16(af[mt], bfr, acc[mt][nt], 0, 0, 0);
        }
      }
    }

    // ---- K-partial reduction through LDS: buf0 = wv0+wv2, buf1 = wv1+wv3 ----
    if (wv >= 2) {
      float* zb = zbuf + (size_t)(wv - 2) * (64 * ZPITCH);
#pragma unroll
      for (int mt = 0; mt < 4; ++mt)
#pragma unroll
        for (int nt = 0; nt < 2; ++nt)
#pragma unroll
          for (int q = 0; q < 4; ++q)
            zb[(mt * 16 + (lane >> 4) * 4 + q) * ZPITCH + nt * 16 + lm] = acc[mt][nt][q];
    }
    __syncthreads();
    if (wv < 2) {
      float* zb = zbuf + (size_t)wv * (64 * ZPITCH);
#pragma unroll
      for (int mt = 0; mt < 4; ++mt)
#pragma unroll
        for (int nt = 0; nt < 2; ++nt)
#pragma unroll
          for (int q = 0; q < 4; ++q)
            zb[(mt * 16 + (lane >> 4) * 4 + q) * ZPITCH + nt * 16 + lm] += acc[mt][nt][q];
    }
    __syncthreads();

    // ---- pointwise gates + cell update (2 hidden units / thread) ----
    {
      float hh2[2];
      float xs = 0.f;
      if (!phB) xs = x[(size_t)ps * TT + t];
      float cc[2] = {c_a, c_b};
#pragma unroll
      for (int u = 0; u < 2; ++u) {
        const int jn = pj + u;
        float zg[4];
#pragma unroll
        for (int g4 = 0; g4 < 4; ++g4) {
          const int n = g4 * 8 + jn;
          float z = zbuf[ps * ZPITCH + n] + zbuf[64 * ZPITCH + ps * ZPITCH + n];
          z += phB ? b1s[n] : (xs * wi0s[n] + b0s[n]);
          zg[g4] = z;
        }
        const float gi = sigm(zg[0]);
        const float gf = sigm(zg[1]);
        const float gg = tanhx(zg[2]);
        const float go = sigm(zg[3]);
        const float c  = gf * cc[u] + gi * gg;
        cc[u]  = c;
        hh2[u] = go * tanhx(c);
      }
      c_a = cc[0]; c_b = cc[1];
      const unsigned int packed =
          (unsigned int)f2bf(hh2[0]) | ((unsigned int)f2bf(hh2[1]) << 16);
      *(unsigned int*)(hbuf + (p & 1) * (BB * HH) + ps * HH + colbase + pj) = packed;
      if (!phB) {
        // stash h1[t] bf16-packed into upper-half fp32 slots of h2 row (s,t)
        *(unsigned int*)(stash + (size_t)ps * 2097152 + (size_t)t * 2048 + 1024 + colbase + pj) = packed;
      } else {
        hp2a = hh2[0]; hp2b = hh2[1];
        if (t == 1023) { hl_a = hh2[0]; hl_b = hh2[1]; }
      }
    }

    grid_barrier(counters, p);
  }

  // epilogue: flush h2[1023], final c1 and h1
  {
    float* o = h2out + (size_t)ps * (TT * HH) + (size_t)1023 * HH + colbase + pj;
    o[0] = hp2a; o[1] = hp2b;
    out[ps * HH + colbase + pj]     = c_a;
    out[ps * HH + colbase + pj + 1] = c_b;
    float* ho = out + BB * HH;
    ho[ps * HH + colbase + pj]     = hl_a;
    ho[ps * HH + colbase + pj + 1] = hl_b;
  }
}

extern "C" void kernel_launch(void* const* d_in, const int* in_sizes, int n_in,
                              void* d_out, int out_size, void* d_ws, size_t ws_size,
                              hipStream_t stream) {
  const float* x   = (const float*)d_in[0];
  const float* Wi0 = (const float*)d_in[1];
  const float* Wh0 = (const float*)d_in[2];
  const float* b0  = (const float*)d_in[3];
  const float* Wi1 = (const float*)d_in[4];
  const float* Wh1 = (const float*)d_in[5];
  const float* b1  = (const float*)d_in[6];

  int* counters         = (int*)d_ws;
  unsigned short* hbuf  = (unsigned short*)((char*)d_ws + 16384);

  fprintf(stderr, "[uniEncodeLSTM] ws_size=%zu bytes\n", ws_size);  // info for tuning

  // zero barrier counters + h double-buffer (ws is poisoned 0xAA before every launch)
  (void)hipMemsetAsync(d_ws, 0, 16384 + 2 * BB * HH * 2, stream);

  (void)hipFuncSetAttribute((const void*)lstm_persist,
                            hipFuncAttributeMaxDynamicSharedMemorySize, SMEM_BYTES);

  lstm_persist<<<dim3(NBLK), dim3(NTHR), SMEM_BYTES, stream>>>(
      x, Wi0, Wh0, b0, Wi1, Wh1, b1, (float*)d_out, counters, hbuf);
}

// Round 2
// 27842.038 us; speedup vs baseline: 1.1400x; 1.1400x over previous
//
#include <hip/hip_runtime.h>
#include <hip/hip_bf16.h>

#define NBLK 128
#define NTHR 256
#define HH   1024
#define BB   64
#define TT   1024
#define SS   8                 // hidden units per block
#define COLS 32                // 4 gates * SS
#define PITCH 1032             // LDS weight pitch (shorts): pad breaks conflicts, keeps 16B align
#define WELEMS (COLS * PITCH)
#define ZPITCH 33
#define SMEM_BYTES (WELEMS * 2 + 2 * 64 * ZPITCH * 4 + 3 * 32 * 4)  // 83328

typedef __bf16 bf16x8 __attribute__((ext_vector_type(8)));
typedef float  f32x4  __attribute__((ext_vector_type(4)));

__device__ __forceinline__ unsigned short f2bf(float x) {
  unsigned int u = __builtin_bit_cast(unsigned int, x);
  u = (u + 0x7fffu + ((u >> 16) & 1u)) >> 16;   // RNE
  return (unsigned short)u;
}
__device__ __forceinline__ float sigm(float x)  { return 1.f / (1.f + __expf(-x)); }
__device__ __forceinline__ float tanhx(float x) { return 2.f / (1.f + __expf(-2.f * x)) - 1.f; }

// Gather one (1024 x 32) column-slice of a (1024 x 4096) fp32 weight into LDS as bf16.
__device__ __forceinline__ void gather_w(const float* __restrict__ Wg, int colbase,
                                         unsigned short* dst) {
  const int tid = threadIdx.x;
  const int n   = tid & 31;
  const int kg  = tid >> 5;  // 0..7
  const int col = (n >> 3) * HH + colbase + (n & 7);
#pragma unroll 8
  for (int kk = 0; kk < 128; ++kk) {
    const int k = kg * 128 + kk;
    dst[n * PITCH + k] = f2bf(Wg[(size_t)k * 4096 + col]);
  }
}

// Two-level barrier: 8 groups x 16 blocks arrive on separate lines; group closers
// arrive on a global counter; final closer releases flag[p]; everyone polls the
// flag READ-ONLY (parallel-served at LLC, no RMW contention on the hot line).
__device__ __forceinline__ void grid_barrier(int* l1, int* g, int* flag, int p, int grp) {
  __syncthreads();   // drains each wave's vmem (incl. h stores) before arrival
  if (threadIdx.x == 0) {
    int a = __hip_atomic_fetch_add(&l1[grp * 2048 + p], 1, __ATOMIC_RELEASE,
                                   __HIP_MEMORY_SCOPE_AGENT);
    if (a == 15) {
      int b = __hip_atomic_fetch_add(&g[p], 1, __ATOMIC_ACQ_REL, __HIP_MEMORY_SCOPE_AGENT);
      if (b == 7)
        __hip_atomic_store(&flag[p], 1, __ATOMIC_RELEASE, __HIP_MEMORY_SCOPE_AGENT);
    }
    while (__hip_atomic_load(&flag[p], __ATOMIC_RELAXED, __HIP_MEMORY_SCOPE_AGENT) == 0)
      __builtin_amdgcn_s_sleep(1);
    (void)__hip_atomic_load(&flag[p], __ATOMIC_ACQUIRE, __HIP_MEMORY_SCOPE_AGENT);
  }
  __syncthreads();
}

__global__ void __launch_bounds__(NTHR, 1) lstm_persist(
    const float* __restrict__ x,   const float* __restrict__ Wi0,
    const float* __restrict__ Wh0, const float* __restrict__ b0,
    const float* __restrict__ Wi1, const float* __restrict__ Wh1,
    const float* __restrict__ b1,  float* out,
    int* l1c, int* gc, int* flag, unsigned short* hbuf) {
  extern __shared__ unsigned short smem_us[];
  unsigned short* w0 = smem_us;                 // transient weight staging
  float* zbuf = (float*)(smem_us + WELEMS);     // [2][64][ZPITCH]
  float* wi0s = zbuf + 2 * 64 * ZPITCH;
  float* b0s  = wi0s + 32;
  float* b1s  = b0s + 32;

  const int tid     = threadIdx.x;
  const int lane    = tid & 63;
  const int wv      = tid >> 6;
  const int colbase = blockIdx.x * SS;
  const int grp     = blockIdx.x >> 4;

  if (tid < 32) {
    const int col = (tid >> 3) * HH + colbase + (tid & 7);
    wi0s[tid] = Wi0[col];
    b0s[tid]  = b0[col];
    b1s[tid]  = b1[col];
  }

  const int kq = wv * 256;
  const int lm = lane & 15;
  const int lk = (lane >> 4) * 8;
  const f32x4 fzero = {0.f, 0.f, 0.f, 0.f};

  // ---- register-resident B fragments (loop-invariant weights) ----
  bf16x8 bW0[16];   // phase A: Wh0; phase B: Wi1   [kc*2+nt]
  bf16x8 bW1[16];   // phase B: Wh1
  gather_w(Wh0, colbase, w0);
  __syncthreads();
#pragma unroll
  for (int kc = 0; kc < 8; ++kc)
#pragma unroll
    for (int nt = 0; nt < 2; ++nt)
      bW0[kc * 2 + nt] =
          *reinterpret_cast<const bf16x8*>(w0 + (nt * 16 + lm) * PITCH + kq + kc * 32 + lk);

  // pointwise ownership: thread -> (sample ps, hidden pair pj, pj+1)
  const int ps = tid >> 2;
  const int pj = (tid & 3) * 2;
  float c_a = 0.f, c_b = 0.f;
  float hp2a = 0.f, hp2b = 0.f;
  float hl_a = 0.f, hl_b = 0.f;

  float* h2out = out + 2 * BB * HH;
  unsigned short* stash = (unsigned short*)h2out;  // bf16 h1-history in upper-half fp32 slots

  bf16x8 pf[32];   // phase B: prefetched Wi1 A-operand (stash[t]) [kc*4+mt]

  for (int p = 0; p < 2048; ++p) {
    const bool phB = (p >= 1024);
    const int  t   = phB ? (p - 1024) : p;
    const unsigned short* hprev = hbuf + ((p + 1) & 1) * (BB * HH);

    if (p == 1024) {  // phase switch (uniform): stage layer-1 weights into registers
      __syncthreads();
      gather_w(Wi1, colbase, w0);
      __syncthreads();
#pragma unroll
      for (int kc = 0; kc < 8; ++kc)
#pragma unroll
        for (int nt = 0; nt < 2; ++nt)
          bW0[kc * 2 + nt] =
              *reinterpret_cast<const bf16x8*>(w0 + (nt * 16 + lm) * PITCH + kq + kc * 32 + lk);
      __syncthreads();
      gather_w(Wh1, colbase, w0);
      __syncthreads();
#pragma unroll
      for (int kc = 0; kc < 8; ++kc)
#pragma unroll
        for (int nt = 0; nt < 2; ++nt)
          bW1[kc * 2 + nt] =
              *reinterpret_cast<const bf16x8*>(w0 + (nt * 16 + lm) * PITCH + kq + kc * 32 + lk);
      // prefetch stash[0] (written at p=0, long visible)
      const unsigned short* sb = stash + 1024;
#pragma unroll
      for (int kc = 0; kc < 8; ++kc) {
        const int k0 = kq + kc * 32 + lk;
#pragma unroll
        for (int mt = 0; mt < 4; ++mt)
          pf[kc * 4 + mt] =
              *reinterpret_cast<const bf16x8*>(sb + (size_t)(mt * 16 + lm) * 2097152 + k0);
      }
    }

    // delayed fp32 h2 write for t-1 (stash[t-1] upper half was consumed last period)
    if (phB && t > 0) {
      float* o = h2out + (size_t)ps * (TT * HH) + (size_t)(t - 1) * HH + colbase + pj;
      o[0] = hp2a; o[1] = hp2b;
    }

    f32x4 acc[4][2];
#pragma unroll
    for (int i = 0; i < 4; ++i)
#pragma unroll
      for (int j = 0; j < 2; ++j) acc[i][j] = fzero;

    if (!phB) {
      // ---- phase A: h_prev @ Wh0 (A from global, B from registers) ----
#pragma unroll
      for (int kc = 0; kc < 8; ++kc) {
        const int k0 = kq + kc * 32 + lk;
        bf16x8 af[4];
#pragma unroll
        for (int mt = 0; mt < 4; ++mt)
          af[mt] = *reinterpret_cast<const bf16x8*>(hprev + (size_t)(mt * 16 + lm) * HH + k0);
#pragma unroll
        for (int nt = 0; nt < 2; ++nt)
#pragma unroll
          for (int mt = 0; mt < 4; ++mt)
            acc[mt][nt] =
                __builtin_amdgcn_mfma_f32_16x16x32_bf16(af[mt], bW0[kc * 2 + nt], acc[mt][nt], 0, 0, 0);
      }
    } else {
      // ---- phase B matmul 1: h1_hist[t] @ Wi1 — A prefetched across the barrier ----
#pragma unroll
      for (int kc = 0; kc < 8; ++kc)
#pragma unroll
        for (int nt = 0; nt < 2; ++nt)
#pragma unroll
          for (int mt = 0; mt < 4; ++mt)
            acc[mt][nt] =
                __builtin_amdgcn_mfma_f32_16x16x32_bf16(pf[kc * 4 + mt], bW0[kc * 2 + nt],
                                                        acc[mt][nt], 0, 0, 0);
      // ---- phase B matmul 2: h_prev @ Wh1 ----
#pragma unroll
      for (int kc = 0; kc < 8; ++kc) {
        const int k0 = kq + kc * 32 + lk;
        bf16x8 af[4];
#pragma unroll
        for (int mt = 0; mt < 4; ++mt)
          af[mt] = *reinterpret_cast<const bf16x8*>(hprev + (size_t)(mt * 16 + lm) * HH + k0);
#pragma unroll
        for (int nt = 0; nt < 2; ++nt)
#pragma unroll
          for (int mt = 0; mt < 4; ++mt)
            acc[mt][nt] =
                __builtin_amdgcn_mfma_f32_16x16x32_bf16(af[mt], bW1[kc * 2 + nt], acc[mt][nt], 0, 0, 0);
      }
      // ---- prefetch stash[t+1] for next period (latency hides under the barrier) ----
      if (t < 1023) {
        const unsigned short* sb = stash + (size_t)(t + 1) * 2048 + 1024;
#pragma unroll
        for (int kc = 0; kc < 8; ++kc) {
          const int k0 = kq + kc * 32 + lk;
#pragma unroll
          for (int mt = 0; mt < 4; ++mt)
            pf[kc * 4 + mt] =
                *reinterpret_cast<const bf16x8*>(sb + (size_t)(mt * 16 + lm) * 2097152 + k0);
        }
      }
    }

    // ---- K-partial reduction through LDS: buf0 = wv0+wv2, buf1 = wv1+wv3 ----
    if (wv >= 2) {
      float* zb = zbuf + (size_t)(wv - 2) * (64 * ZPITCH);
#pragma unroll
      for (int mt = 0; mt < 4; ++mt)
#pragma unroll
        for (int nt = 0; nt < 2; ++nt)
#pragma unroll
          for (int q = 0; q < 4; ++q)
            zb[(mt * 16 + (lane >> 4) * 4 + q) * ZPITCH + nt * 16 + lm] = acc[mt][nt][q];
    }
    __syncthreads();
    if (wv < 2) {
      float* zb = zbuf + (size_t)wv * (64 * ZPITCH);
#pragma unroll
      for (int mt = 0; mt < 4; ++mt)
#pragma unroll
        for (int nt = 0; nt < 2; ++nt)
#pragma unroll
          for (int q = 0; q < 4; ++q)
            zb[(mt * 16 + (lane >> 4) * 4 + q) * ZPITCH + nt * 16 + lm] += acc[mt][nt][q];
    }
    __syncthreads();

    // ---- pointwise gates + cell update (2 hidden units / thread) ----
    {
      float hh2[2];
      float xs = 0.f;
      if (!phB) xs = x[(size_t)ps * TT + t];
      float cc[2] = {c_a, c_b};
#pragma unroll
      for (int u = 0; u < 2; ++u) {
        const int jn = pj + u;
        float zg[4];
#pragma unroll
        for (int g4 = 0; g4 < 4; ++g4) {
          const int n = g4 * 8 + jn;
          float z = zbuf[ps * ZPITCH + n] + zbuf[64 * ZPITCH + ps * ZPITCH + n];
          z += phB ? b1s[n] : (xs * wi0s[n] + b0s[n]);
          zg[g4] = z;
        }
        const float gi = sigm(zg[0]);
        const float gf = sigm(zg[1]);
        const float gg = tanhx(zg[2]);
        const float go = sigm(zg[3]);
        const float c  = gf * cc[u] + gi * gg;
        cc[u]  = c;
        hh2[u] = go * tanhx(c);
      }
      c_a = cc[0]; c_b = cc[1];
      const unsigned int packed =
          (unsigned int)f2bf(hh2[0]) | ((unsigned int)f2bf(hh2[1]) << 16);
      *(unsigned int*)(hbuf + (p & 1) * (BB * HH) + ps * HH + colbase + pj) = packed;
      if (!phB) {
        *(unsigned int*)(stash + (size_t)ps * 2097152 + (size_t)t * 2048 + 1024 + colbase + pj) = packed;
      } else {
        hp2a = hh2[0]; hp2b = hh2[1];
        if (t == 1023) { hl_a = hh2[0]; hl_b = hh2[1]; }
      }
    }

    grid_barrier(l1c, gc, flag, p, grp);
  }

  // epilogue: flush h2[1023], final c1 and h1
  {
    float* o = h2out + (size_t)ps * (TT * HH) + (size_t)1023 * HH + colbase + pj;
    o[0] = hp2a; o[1] = hp2b;
    out[ps * HH + colbase + pj]     = c_a;
    out[ps * HH + colbase + pj + 1] = c_b;
    float* ho = out + BB * HH;
    ho[ps * HH + colbase + pj]     = hl_a;
    ho[ps * HH + colbase + pj + 1] = hl_b;
  }
}

extern "C" void kernel_launch(void* const* d_in, const int* in_sizes, int n_in,
                              void* d_out, int out_size, void* d_ws, size_t ws_size,
                              hipStream_t stream) {
  const float* x   = (const float*)d_in[0];
  const float* Wi0 = (const float*)d_in[1];
  const float* Wh0 = (const float*)d_in[2];
  const float* b0  = (const float*)d_in[3];
  const float* Wi1 = (const float*)d_in[4];
  const float* Wh1 = (const float*)d_in[5];
  const float* b1  = (const float*)d_in[6];

  // ws layout: [0,64K) l1 counters (8 groups x 2048), [64K,72K) global counters,
  // [72K,80K) release flags, [80K, 80K+256K) h double-buffer
  int* l1c  = (int*)d_ws;
  int* gc   = (int*)((char*)d_ws + 65536);
  int* flag = (int*)((char*)d_ws + 73728);
  unsigned short* hbuf = (unsigned short*)((char*)d_ws + 81920);

  (void)hipMemsetAsync(d_ws, 0, 81920 + 2 * BB * HH * 2, stream);

  (void)hipFuncSetAttribute((const void*)lstm_persist,
                            hipFuncAttributeMaxDynamicSharedMemorySize, SMEM_BYTES);

  lstm_persist<<<dim3(NBLK), dim3(NTHR), SMEM_BYTES, stream>>>(
      x, Wi0, Wh0, b0, Wi1, Wh1, b1, (float*)d_out, l1c, gc, flag, hbuf);
}